// Round 1
// baseline (822.013 us; speedup 1.0000x reference)
//
#include <hip/hip_runtime.h>

#define HIDDEN 128
#define BM 128          // rows per block
#define LDSS 136        // padded LDS row stride (bf16 elems): 272 B, 16B-aligned, spreads banks
#define BATCH 80000

typedef __attribute__((ext_vector_type(8))) short short8;   // 8 bf16 = 4 VGPRs (MFMA A/B frag)
typedef __attribute__((ext_vector_type(4))) float f32x4;    // MFMA C/D frag

__device__ __forceinline__ unsigned short f2bf(float f) {
  union { float f; unsigned u; } cv; cv.f = f;
  // round-to-nearest-even fp32 -> bf16
  return (unsigned short)((cv.u + 0x7fffu + ((cv.u >> 16) & 1u)) >> 16);
}

// w0t[n][k] = W0[k][n]                      (plain transpose, bf16)
// w1t[n][s] = W1[perm(s)][n]  where perm(s) = ((s>>2)&7)*16 + (s>>5)*4 + (s&3)
// The perm matches the storage order in which layer-1 lanes can write h1
// contiguously (s = quad*32 + nt*4 + r  for  k_actual = nt*16 + quad*4 + r).
__global__ void prep_w_kernel(const float* __restrict__ W0,
                              const float* __restrict__ W1,
                              unsigned short* __restrict__ w0t,
                              unsigned short* __restrict__ w1t) {
  int idx = blockIdx.x * blockDim.x + threadIdx.x;  // 0..16383
  int n = idx >> 7;
  int s = idx & 127;
  w0t[idx] = f2bf(W0[s * HIDDEN + n]);
  int k = ((s >> 2) & 7) * 16 + (s >> 5) * 4 + (s & 3);
  w1t[idx] = f2bf(W1[k * HIDDEN + n]);
}

// out = relu(relu(x[:80000] @ W0) @ W1)
// Block: 256 thr = 4 waves; each wave owns 32 rows (2 m-tiles of 16).
// Both layers use SWAPPED mfma operands: mfma(Wfrag, Xfrag, acc) -> D = out^T tile,
// so each lane holds 4 CONSECUTIVE output columns (n = nt*16 + quad*4 + r):
//   layer 1 -> h1 packs into 8x ds_write_b128 (k-permuted storage, matched by w1t)
//   layer 2 -> out packs into 16x global_store_dwordx4
// h1 rows are wave-private -> no __syncthreads anywhere; wave-local lgkmcnt fence only.
__global__ __launch_bounds__(256) void mlp2_kernel(
    const float* __restrict__ x,
    const unsigned short* __restrict__ w0t,
    const unsigned short* __restrict__ w1t,
    float* __restrict__ out) {
  __shared__ unsigned short lds[BM * LDSS];  // h1 tile only (34816 B)

  const int tid = threadIdx.x;
  const int w    = tid >> 6;    // wave id 0..3
  const int l    = tid & 63;    // lane
  const int c16  = l & 15;      // MFMA i/j index
  const int quad = l >> 4;      // MFMA k-group / row-group
  const int blockRow = blockIdx.x * BM;
  const int wrow = w * 32;      // wave's first row within block

  // ---- Layer 1: x fragments straight from global (fp32 -> bf16 in regs) ----
  // B-frag layout: B[k][j=c16] = x[row = wrow+mt*16+c16][k = kk*32+quad*8+jj]
  short8 xf[2][4];
  #pragma unroll
  for (int mt = 0; mt < 2; ++mt) {
    const float* xrow = x + (size_t)(blockRow + wrow + mt * 16 + c16) * HIDDEN;
    #pragma unroll
    for (int kk = 0; kk < 4; ++kk) {
      float4 u = *(const float4*)(xrow + kk * 32 + quad * 8);
      float4 v = *(const float4*)(xrow + kk * 32 + quad * 8 + 4);
      short8 f;
      f[0] = (short)f2bf(u.x); f[1] = (short)f2bf(u.y);
      f[2] = (short)f2bf(u.z); f[3] = (short)f2bf(u.w);
      f[4] = (short)f2bf(v.x); f[5] = (short)f2bf(v.y);
      f[6] = (short)f2bf(v.z); f[7] = (short)f2bf(v.w);
      xf[mt][kk] = f;
    }
  }

  f32x4 acc[2][8];
  #pragma unroll
  for (int mt = 0; mt < 2; ++mt)
    #pragma unroll
    for (int nt = 0; nt < 8; ++nt)
      acc[mt][nt] = (f32x4){0.f, 0.f, 0.f, 0.f};

  #pragma unroll
  for (int kk = 0; kk < 4; ++kk) {
    const int k0 = kk * 32;
    #pragma unroll
    for (int nt = 0; nt < 8; ++nt) {
      // A-frag: A[i = nt*16+c16][k] = W0^T[n][k], contiguous 16 B, L1/L2-resident
      short8 wf = *(const short8*)&w0t[(nt * 16 + c16) * HIDDEN + k0 + quad * 8];
      acc[0][nt] = __builtin_amdgcn_mfma_f32_16x16x32_bf16(wf, xf[0][kk], acc[0][nt], 0, 0, 0);
      acc[1][nt] = __builtin_amdgcn_mfma_f32_16x16x32_bf16(wf, xf[1][kk], acc[1][nt], 0, 0, 0);
    }
  }

  // ---- h1 -> LDS, vectorized. Lane holds h[m = mt*16+c16][n = nt*16+quad*4+r].
  // Storage index s = quad*32 + nt*4 + r  (contiguous per lane; w1t rows use perm(s)).
  #pragma unroll
  for (int mt = 0; mt < 2; ++mt) {
    const int row = wrow + mt * 16 + c16;
    #pragma unroll
    for (int g = 0; g < 4; ++g) {   // g covers nt = 2g, 2g+1
      short8 h;
      #pragma unroll
      for (int r = 0; r < 4; ++r) {
        h[r]     = (short)f2bf(fmaxf(acc[mt][2 * g    ][r], 0.f));
        h[4 + r] = (short)f2bf(fmaxf(acc[mt][2 * g + 1][r], 0.f));
      }
      *(short8*)&lds[row * LDSS + quad * 32 + g * 8] = h;
    }
  }
  // h1 rows are wave-private: wave-local fence instead of __syncthreads.
  asm volatile("s_waitcnt lgkmcnt(0)" ::: "memory");
  __builtin_amdgcn_sched_barrier(0);   // rule #18: keep reg-only ops from hoisting past the wait

  // ---- Layer 2: B-frag = h1 from LDS (permuted storage, matches w1t) ----
  short8 hf[2][4];
  #pragma unroll
  for (int mt = 0; mt < 2; ++mt)
    #pragma unroll
    for (int kk = 0; kk < 4; ++kk)
      hf[mt][kk] = *(const short8*)&lds[(wrow + mt * 16 + c16) * LDSS + kk * 32 + quad * 8];

  #pragma unroll
  for (int mt = 0; mt < 2; ++mt)
    #pragma unroll
    for (int nt = 0; nt < 8; ++nt)
      acc[mt][nt] = (f32x4){0.f, 0.f, 0.f, 0.f};

  #pragma unroll
  for (int kk = 0; kk < 4; ++kk) {
    const int k0 = kk * 32;
    #pragma unroll
    for (int nt = 0; nt < 8; ++nt) {
      short8 wf = *(const short8*)&w1t[(nt * 16 + c16) * HIDDEN + k0 + quad * 8];
      acc[0][nt] = __builtin_amdgcn_mfma_f32_16x16x32_bf16(wf, hf[0][kk], acc[0][nt], 0, 0, 0);
      acc[1][nt] = __builtin_amdgcn_mfma_f32_16x16x32_bf16(wf, hf[1][kk], acc[1][nt], 0, 0, 0);
    }
  }

  // ---- relu + out: lane holds out[m = mt*16+c16][n = nt*16+quad*4 .. +3] -> float4 store
  #pragma unroll
  for (int mt = 0; mt < 2; ++mt) {
    float* orow = out + (size_t)(blockRow + wrow + mt * 16 + c16) * HIDDEN;
    #pragma unroll
    for (int nt = 0; nt < 8; ++nt) {
      float4 o;
      o.x = fmaxf(acc[mt][nt][0], 0.f);
      o.y = fmaxf(acc[mt][nt][1], 0.f);
      o.z = fmaxf(acc[mt][nt][2], 0.f);
      o.w = fmaxf(acc[mt][nt][3], 0.f);
      *(float4*)(orow + nt * 16 + quad * 4) = o;
    }
  }
}

extern "C" void kernel_launch(void* const* d_in, const int* in_sizes, int n_in,
                              void* d_out, int out_size, void* d_ws, size_t ws_size,
                              hipStream_t stream) {
  // Inputs: 0:x 1:hist0 2:hist1 3:W0 4:W1 5:n_id 6:batch_size
  // hist0/hist1/n_id are dead code for the returned output (pull reads pre-update hist;
  // rows >= batch never reach out); out = relu(relu(x[:80000] @ W0) @ W1).
  const float* x  = (const float*)d_in[0];
  const float* W0 = (const float*)d_in[3];
  const float* W1 = (const float*)d_in[4];
  float* out = (float*)d_out;

  unsigned short* w0t = (unsigned short*)d_ws;                 // 16384 bf16
  unsigned short* w1t = w0t + HIDDEN * HIDDEN;                 // 16384 bf16 (64 KB total)

  prep_w_kernel<<<HIDDEN * HIDDEN / 256, 256, 0, stream>>>(W0, W1, w0t, w1t);
  mlp2_kernel<<<BATCH / BM, 256, 0, stream>>>(x, w0t, w1t, out);
}